// Round 12
// baseline (139.818 us; speedup 1.0000x reference)
//
#include <hip/hip_runtime.h>
#include <stdint.h>

#define H 8
#define DMODEL 1024
#define DCON 768
#define DPOS 256
#define TT 8192

typedef unsigned short u16;
typedef __attribute__((ext_vector_type(8))) short bf16x8;
typedef __attribute__((ext_vector_type(4))) short bf16x4;
typedef __attribute__((ext_vector_type(4))) float f32x4;

typedef __attribute__((address_space(1))) const void as1_void;
typedef __attribute__((address_space(3))) void as3_void;

__device__ __forceinline__ void async_copy16(const void* g, void* l) {
  __builtin_amdgcn_global_load_lds((as1_void*)g, (as3_void*)l, 16, 0, 0);
}

__device__ __forceinline__ short f2bf(float x) {
  unsigned u = __builtin_bit_cast(unsigned, x);
  u = (u + 0x7fffu + ((u >> 16) & 1u)) >> 16;
  return (short)u;
}

__device__ __forceinline__ short f2bf_trunc(float x) {
  return (short)(__builtin_bit_cast(unsigned, x) >> 16);
}

__device__ __forceinline__ float bf2f(u16 v) {
  return __builtin_bit_cast(float, (unsigned)v << 16);
}

// ---------------- fused prep kernel (one dispatch) ----------------
__global__ __launch_bounds__(256) void prep_kernel(
    const float* __restrict__ inp, u16* __restrict__ X,
    const float* __restrict__ wq1, const float* __restrict__ wk1, const float* __restrict__ wv1,
    const float* __restrict__ wq2, const float* __restrict__ wk2, const float* __restrict__ wv2,
    const float* __restrict__ wp1, const float* __restrict__ wp2,
    u16* __restrict__ W1t, u16* __restrict__ W2t, u16* __restrict__ Wpt) {
  const int bid = blockIdx.x, tid = threadIdx.x;
  if (bid < 8192) {
    size_t i = (size_t)bid * 256 + tid;
    const float4 v = *(const float4*)(inp + i * 4);
    bf16x4 o;
    o[0] = f2bf(v.x); o[1] = f2bf(v.y); o[2] = f2bf(v.z); o[3] = f2bf(v.w);
    *(bf16x4*)(X + i * 4) = o;
  } else if (bid < 14336) {
    const int w2 = (bid >= 12800);
    const int K = w2 ? 256 : 768;
    const float* wq = w2 ? wq2 : wq1;
    const float* wk = w2 ? wk2 : wk1;
    const float* wv = w2 ? wv2 : wv1;
    u16* Wt = w2 ? W2t : W1t;
    int idx = (bid - (w2 ? 12800 : 8192)) * 256 + tid;
    int n = idx / K, r = idx % K;
    int h = n / 192, rem = n % 192, op = rem >> 6, d = rem & 63;
    const float* src = (op == 0) ? wq : (op == 1) ? wk : wv;
    Wt[idx] = (u16)f2bf(src[((size_t)h * K + r) * 64 + d]);
  } else {
    const int p2 = (bid >= 15872);
    const float* w = p2 ? wp2 : wp1;
    const int Ncols = p2 ? 256 : 768;
    u16* Wt = Wpt + (p2 ? 768 * 512 : 0);
    int idx = (bid - (p2 ? 15872 : 14336)) * 256 + tid;
    int c = idx >> 9, j = idx & 511;
    Wt[idx] = (u16)f2bf(w[(size_t)j * Ncols + c]);
  }
}

// ---------------- merged QKV GEMM (uniform blocks) ----------------
// grid (64, 12): 768 blocks = exactly 3 CU-waves, all identical.
// Each block runs TWO passes sequentially over the same 128x128 output panel:
//   pass 0: content    (W1t, K=768, aoff=0,   doff=0,  12 K-steps)
//   pass 1: positional (W2t, K=256, aoff=768, doff=64,  4 K-steps)
// LDS/acc reused across passes; pass-top __syncthreads covers buffer reuse.
// Epilogue scatters Q,K (H,T,128) and V direct-transposed (H*B,128,1024).
__global__ __launch_bounds__(256) void gemm_qkv(
    const u16* __restrict__ Xb, const u16* __restrict__ W1t, const u16* __restrict__ W2t,
    u16* __restrict__ q_out, u16* __restrict__ k_out, u16* __restrict__ v_out) {
  __shared__ char smem[65536];
  auto Asp = [&](int buf) -> char* { return smem + buf * 16384; };
  auto Bsp = [&](int buf) -> char* { return smem + 32768 + buf * 16384; };
  const int tid = threadIdx.x;
  const int lane = tid & 63, wid = tid >> 6;
  const int m0 = blockIdx.x * 128;
  const int n0 = blockIdx.y * 128;

  const int lr = lane >> 3, lcb = (lane & 7) << 4;
  const int mwq = (wid >> 1) * 64, nwq = (wid & 1) * 64;
  const int ml = lane & 15, kg = (lane >> 4) << 4;

  for (int pass = 0; pass < 2; ++pass) {
    const u16* Bt = pass ? W2t : W1t;
    const int K    = pass ? 256 : 768;
    const int aoff = pass ? 768 : 0;
    const int doff = pass ? 64 : 0;
    const int KT = K >> 6;

    auto stage = [&](int kt, int buf) {
#pragma unroll
      for (int s = 0; s < 4; ++s) {
        int r = wid * 32 + s * 8 + lr;
        int cb = lcb ^ ((r & 7) << 4);
        const char* g = (const char*)(Xb + (size_t)(m0 + r) * DMODEL + aoff + kt * 64) + cb;
        async_copy16(g, Asp(buf) + (wid * 32 + s * 8) * 128);
      }
#pragma unroll
      for (int s = 0; s < 4; ++s) {
        int r = wid * 32 + s * 8 + lr;
        int cb = lcb ^ ((r & 7) << 4);
        const char* g = (const char*)(Bt + (size_t)(n0 + r) * K + kt * 64) + cb;
        async_copy16(g, Bsp(buf) + (wid * 32 + s * 8) * 128);
      }
    };

    f32x4 acc[4][4];
    const f32x4 fz = {0.f, 0.f, 0.f, 0.f};
#pragma unroll
    for (int i = 0; i < 4; ++i)
#pragma unroll
      for (int j = 0; j < 4; ++j) acc[i][j] = fz;

    auto compute = [&](int buf) {
#pragma unroll
      for (int ks = 0; ks < 2; ++ks) {
        bf16x8 af[4], bfr[4];
#pragma unroll
        for (int f = 0; f < 4; ++f) {
          int rowa = mwq + f * 16 + ml;
          af[f] = *(const bf16x8*)(Asp(buf) + rowa * 128 + ((ks * 64 + kg) ^ ((rowa & 7) << 4)));
          int rowb = nwq + f * 16 + ml;
          bfr[f] = *(const bf16x8*)(Bsp(buf) + rowb * 128 + ((ks * 64 + kg) ^ ((rowb & 7) << 4)));
        }
#pragma unroll
        for (int fm = 0; fm < 4; ++fm)
#pragma unroll
          for (int fn = 0; fn < 4; ++fn)
            acc[fm][fn] = __builtin_amdgcn_mfma_f32_16x16x32_bf16(af[fm], bfr[fn], acc[fm][fn], 0, 0, 0);
      }
    };

    if (pass) __syncthreads();  // all waves done with pass-0 LDS reads
    stage(0, 0);
    __syncthreads();
    for (int kt = 0; kt < KT - 1; ++kt) {
      stage(kt + 1, (kt + 1) & 1);
      compute(kt & 1);
      __syncthreads();
    }
    compute((KT - 1) & 1);

#pragma unroll
    for (int fm = 0; fm < 4; ++fm) {
#pragma unroll
      for (int fn = 0; fn < 4; ++fn) {
        int nb = n0 + nwq + fn * 16;
        int h = nb / 192, rem = nb % 192, op = rem >> 6, db = rem & 63;
        int d = doff + db + ml;
        int t0 = m0 + mwq + fm * 16 + (lane >> 4) * 4;
        if (op == 2) {
          // V direct-transposed: Vtg[(h*8+b)*128 + d][t], 4 consecutive t -> bf16x4
          int b = t0 >> 10, l = t0 & 1023;
          bf16x4 o4;
#pragma unroll
          for (int r = 0; r < 4; ++r) o4[r] = f2bf(acc[fm][fn][r]);
          *(bf16x4*)(v_out + ((size_t)(h * 8 + b) * 128 + d) * 1024 + l) = o4;
        } else {
          u16* dst = (op == 0) ? q_out : k_out;
#pragma unroll
          for (int r = 0; r < 4; ++r)
            dst[((size_t)h * TT + t0 + r) * 128 + d] = (u16)f2bf(acc[fm][fn][r]);
        }
      }
    }
  }
}

// ---------------- proj GEMM (bf16 Z epilogue) ----------------
__global__ __launch_bounds__(256) void gemm_proj(
    const u16* __restrict__ O1, const u16* __restrict__ O2, const u16* __restrict__ Wpt,
    const u16* __restrict__ Xb, u16* __restrict__ Zb) {
  __shared__ char smem[65536];
  auto Asp = [&](int buf) -> char* { return smem + buf * 16384; };
  auto Bsp = [&](int buf) -> char* { return smem + 32768 + buf * 16384; };
  const int tid = threadIdx.x;
  const int lane = tid & 63, wid = tid >> 6;
  const int m0 = blockIdx.x * 128, n0 = blockIdx.y * 128;
  const u16* A = (blockIdx.y < 6) ? O1 : O2;
  const int KT = 8;  // K = 512

  const int lr = lane >> 3, lcb = (lane & 7) << 4;

  auto stage = [&](int kt, int buf) {
#pragma unroll
    for (int s = 0; s < 4; ++s) {
      int r = wid * 32 + s * 8 + lr;
      int cb = lcb ^ ((r & 7) << 4);
      const char* g = (const char*)(A + (size_t)(m0 + r) * 512 + kt * 64) + cb;
      async_copy16(g, Asp(buf) + (wid * 32 + s * 8) * 128);
    }
#pragma unroll
    for (int s = 0; s < 4; ++s) {
      int r = wid * 32 + s * 8 + lr;
      int cb = lcb ^ ((r & 7) << 4);
      const char* g = (const char*)(Wpt + (size_t)(n0 + r) * 512 + kt * 64) + cb;
      async_copy16(g, Bsp(buf) + (wid * 32 + s * 8) * 128);
    }
  };

  f32x4 acc[4][4];
  const f32x4 fz = {0.f, 0.f, 0.f, 0.f};
#pragma unroll
  for (int i = 0; i < 4; ++i)
#pragma unroll
    for (int j = 0; j < 4; ++j) acc[i][j] = fz;

  const int mwq = (wid >> 1) * 64, nwq = (wid & 1) * 64;
  const int ml = lane & 15, kg = (lane >> 4) << 4;

  auto compute = [&](int buf) {
#pragma unroll
    for (int ks = 0; ks < 2; ++ks) {
      bf16x8 af[4], bfr[4];
#pragma unroll
      for (int f = 0; f < 4; ++f) {
        int rowa = mwq + f * 16 + ml;
        af[f] = *(const bf16x8*)(Asp(buf) + rowa * 128 + ((ks * 64 + kg) ^ ((rowa & 7) << 4)));
        int rowb = nwq + f * 16 + ml;
        bfr[f] = *(const bf16x8*)(Bsp(buf) + rowb * 128 + ((ks * 64 + kg) ^ ((rowb & 7) << 4)));
      }
#pragma unroll
      for (int fm = 0; fm < 4; ++fm)
#pragma unroll
        for (int fn = 0; fn < 4; ++fn)
          acc[fm][fn] = __builtin_amdgcn_mfma_f32_16x16x32_bf16(af[fm], bfr[fn], acc[fm][fn], 0, 0, 0);
    }
  };

  stage(0, 0);
  __syncthreads();
  for (int kt = 0; kt < KT - 1; ++kt) {
    stage(kt + 1, (kt + 1) & 1);
    compute(kt & 1);
    __syncthreads();
  }
  compute((KT - 1) & 1);

#pragma unroll
  for (int fm = 0; fm < 4; ++fm)
#pragma unroll
    for (int fn = 0; fn < 4; ++fn) {
      int col = n0 + nwq + fn * 16 + ml;
#pragma unroll
      for (int r = 0; r < 4; ++r) {
        int t = m0 + mwq + fm * 16 + (lane >> 4) * 4 + r;
        float zv = acc[fm][fn][r] + bf2f(Xb[(size_t)t * DMODEL + col]);
        Zb[(size_t)t * DMODEL + col] = (u16)f2bf(zv);
      }
    }
}

// ---------------- flash attention: 4 fat waves x 32 q-rows (frozen at r9/r11) ----------------
// grid 512 = qt(8) x hb(64); bid%8 == hb%8 (XCD-pinned K/V). 256 threads.
// LDS-staged K/V (double-buffered, counted-vmcnt 2-deep pipeline). Each kf/vf
// LDS read feeds both q-subtiles' MFMAs. Row-sum l via ones-vector MFMA.
__global__ __launch_bounds__(256, 2) void attn_kernel(
    const u16* __restrict__ Qg, const u16* __restrict__ Kg, const u16* __restrict__ Vtg,
    u16* __restrict__ O1g, u16* __restrict__ O2g) {
  extern __shared__ char smem[];
  const int tid = threadIdx.x, lane = tid & 63, wid = tid >> 6;
  const int bid = blockIdx.x;
  const int qt = bid >> 6, hb = bid & 63, h = hb >> 3, b = hb & 7;
  const int ml = lane & 15, kgrp = lane >> 4, kg = kgrp << 4;

  const size_t qkbase = ((size_t)h * TT + b * 1024) * 128;
  const char* Kbyte = (const char*)(Kg + qkbase);
  const char* Vbyte = (const char*)(Vtg + (size_t)hb * 128 * 1024);

  bf16x8 qf[2][4];
#pragma unroll
  for (int qs = 0; qs < 2; ++qs) {
    const char* qp = (const char*)(Qg + qkbase + (size_t)(qt * 128 + wid * 32 + qs * 16 + ml) * 128);
#pragma unroll
    for (int kk = 0; kk < 4; ++kk) qf[qs][kk] = *(const bf16x8*)(qp + kk * 64 + kg);
  }

  auto stage = [&](int kv0, int buf) {
#pragma unroll
    for (int s = 0; s < 4; ++s) {
      int c = wid * 256 + s * 64 + lane;
      int row = c >> 4, i16 = (c & 15) << 4;
      const char* g = Kbyte + (size_t)(kv0 + row) * 256 + (i16 ^ ((row & 7) << 4));
      async_copy16(g, smem + buf * 16384 + c * 16);
    }
#pragma unroll
    for (int s = 0; s < 4; ++s) {
      int c = wid * 256 + s * 64 + lane;
      int row = c >> 3, i16 = (c & 7) << 4;
      const char* g = Vbyte + (size_t)row * 2048 + kv0 * 2 + (i16 ^ ((row & 7) << 4));
      async_copy16(g, smem + 32768 + buf * 16384 + c * 16);
    }
  };

  f32x4 oacc[2][8];
  f32x4 lacc[2];
  const f32x4 fz = {0.f, 0.f, 0.f, 0.f};
#pragma unroll
  for (int qs = 0; qs < 2; ++qs) {
    lacc[qs] = fz;
#pragma unroll
    for (int i = 0; i < 8; ++i) oacc[qs][i] = fz;
  }
  const float C2 = 0.045084219952754514f;  // log2(e)/32
  bf16x8 ones;
#pragma unroll
  for (int j = 0; j < 8; ++j) ones[j] = (short)0x3F80;  // bf16 1.0

  char* Pw = smem + 65536 + wid * 4096;

  asm volatile("s_waitcnt vmcnt(0)" ::: "memory");
  stage(0, 0);
  stage(64, 1);

  for (int it = 0; it < 16; ++it) {
    const int cur = it & 1;
    if (it < 15) asm volatile("s_waitcnt vmcnt(8)" ::: "memory");
    else         asm volatile("s_waitcnt vmcnt(0)" ::: "memory");
    __builtin_amdgcn_sched_barrier(0);
    __builtin_amdgcn_s_barrier();
    __builtin_amdgcn_sched_barrier(0);

    f32x4 s4[2][4];
#pragma unroll
    for (int qs = 0; qs < 2; ++qs)
#pragma unroll
      for (int i = 0; i < 4; ++i) s4[qs][i] = fz;
    __builtin_amdgcn_s_setprio(1);
#pragma unroll
    for (int kk = 0; kk < 4; ++kk) {
#pragma unroll
      for (int rt = 0; rt < 4; ++rt) {
        int row = rt * 16 + ml;
        bf16x8 kf = *(const bf16x8*)(smem + cur * 16384 + row * 256 + ((kk * 64 + kg) ^ ((row & 7) << 4)));
        s4[0][rt] = __builtin_amdgcn_mfma_f32_16x16x32_bf16(kf, qf[0][kk], s4[0][rt], 0, 0, 0);
        s4[1][rt] = __builtin_amdgcn_mfma_f32_16x16x32_bf16(kf, qf[1][kk], s4[1][rt], 0, 0, 0);
      }
    }
    __builtin_amdgcn_s_setprio(0);

#pragma unroll
    for (int qs = 0; qs < 2; ++qs) {
#pragma unroll
      for (int rt = 0; rt < 4; ++rt) {
        bf16x4 pv;
#pragma unroll
        for (int r = 0; r < 4; ++r) pv[r] = f2bf_trunc(exp2f(s4[qs][rt][r] * C2));
        int cb = (rt * 32 + (kgrp << 3)) ^ ((ml & 7) << 4);
        *(bf16x4*)(Pw + qs * 2048 + ml * 128 + cb) = pv;
      }
    }

    bf16x8 pa[2][2];
#pragma unroll
    for (int qs = 0; qs < 2; ++qs)
#pragma unroll
      for (int ks = 0; ks < 2; ++ks)
        pa[qs][ks] = *(const bf16x8*)(Pw + qs * 2048 + ml * 128 + ((ks * 64 + kg) ^ ((ml & 7) << 4)));

    __builtin_amdgcn_s_setprio(1);
    lacc[0] = __builtin_amdgcn_mfma_f32_16x16x32_bf16(pa[0][0], ones, lacc[0], 0, 0, 0);
    lacc[0] = __builtin_amdgcn_mfma_f32_16x16x32_bf16(pa[0][1], ones, lacc[0], 0, 0, 0);
    lacc[1] = __builtin_amdgcn_mfma_f32_16x16x32_bf16(pa[1][0], ones, lacc[1], 0, 0, 0);
    lacc[1] = __builtin_amdgcn_mfma_f32_16x16x32_bf16(pa[1][1], ones, lacc[1], 0, 0, 0);
#pragma unroll
    for (int vt = 0; vt < 8; ++vt) {
#pragma unroll
      for (int ks = 0; ks < 2; ++ks) {
        int row = vt * 16 + ml;
        bf16x8 vf = *(const bf16x8*)(smem + 32768 + cur * 16384 + row * 128 + ((ks * 64 + kg) ^ ((row & 7) << 4)));
        oacc[0][vt] = __builtin_amdgcn_mfma_f32_16x16x32_bf16(pa[0][ks], vf, oacc[0][vt], 0, 0, 0);
        oacc[1][vt] = __builtin_amdgcn_mfma_f32_16x16x32_bf16(pa[1][ks], vf, oacc[1][vt], 0, 0, 0);
      }
    }
    __builtin_amdgcn_s_setprio(0);

    __builtin_amdgcn_sched_barrier(0);
    __builtin_amdgcn_s_barrier();
    __builtin_amdgcn_sched_barrier(0);
    if (it < 14) stage((it + 2) * 64, cur);
  }

#pragma unroll
  for (int qs = 0; qs < 2; ++qs) {
    float rl[4];
#pragma unroll
    for (int r = 0; r < 4; ++r) rl[r] = 1.f / lacc[qs][r];
#pragma unroll
    for (int vt = 0; vt < 8; ++vt) {
#pragma unroll
      for (int r = 0; r < 4; ++r) {
        int trow = b * 1024 + qt * 128 + wid * 32 + qs * 16 + kgrp * 4 + r;
        float ov = oacc[qs][vt][r] * rl[r];
        if (vt < 4)
          O1g[(size_t)trow * 512 + h * 64 + vt * 16 + ml] = (u16)f2bf(ov);
        else
          O2g[(size_t)trow * 512 + h * 64 + (vt - 4) * 16 + ml] = (u16)f2bf(ov);
      }
    }
  }
}

// ---------------- layernorm (bf16 Z input) ----------------
__global__ __launch_bounds__(256) void ln_kernel(const u16* __restrict__ Zb, const float* __restrict__ ga,
                                                 const float* __restrict__ gb, float* __restrict__ out) {
  int row = blockIdx.x, tid = threadIdx.x;
  bf16x4 zv = *(const bf16x4*)(Zb + (size_t)row * 1024 + tid * 4);
  float v0 = bf2f((u16)zv[0]), v1 = bf2f((u16)zv[1]), v2 = bf2f((u16)zv[2]), v3 = bf2f((u16)zv[3]);
  float s = v0 + v1 + v2 + v3;
  float s2 = v0 * v0 + v1 * v1 + v2 * v2 + v3 * v3;
#pragma unroll
  for (int d = 1; d < 64; d <<= 1) {
    s += __shfl_xor(s, d);
    s2 += __shfl_xor(s2, d);
  }
  __shared__ float red[8];
  int wid = tid >> 6, lane = tid & 63;
  if (lane == 0) { red[wid] = s; red[4 + wid] = s2; }
  __syncthreads();
  float ts = red[0] + red[1] + red[2] + red[3];
  float ts2 = red[4] + red[5] + red[6] + red[7];
  float mu = ts * (1.f / 1024.f);
  float var = (ts2 - ts * mu) * (1.f / 1023.f);
  float inv = 1.f / (sqrtf(var) + 0.001f);
  const float4 a = *(const float4*)(ga + tid * 4);
  const float4 bb = *(const float4*)(gb + tid * 4);
  float4 o;
  o.x = (v0 - mu) * inv * a.x + bb.x;
  o.y = (v1 - mu) * inv * a.y + bb.y;
  o.z = (v2 - mu) * inv * a.z + bb.z;
  o.w = (v3 - mu) * inv * a.w + bb.w;
  *(float4*)(out + (size_t)row * 1024 + tid * 4) = o;
}

// ---------------- launch ----------------
extern "C" void kernel_launch(void* const* d_in, const int* in_sizes, int n_in,
                              void* d_out, int out_size, void* d_ws, size_t ws_size,
                              hipStream_t stream) {
  (void)in_sizes; (void)n_in; (void)out_size; (void)ws_size;
  const float* inp = (const float*)d_in[0];
  const float* w_qs1 = (const float*)d_in[1];
  const float* w_ks1 = (const float*)d_in[2];
  const float* w_vs1 = (const float*)d_in[3];
  const float* w_qs2 = (const float*)d_in[4];
  const float* w_ks2 = (const float*)d_in[5];
  const float* w_vs2 = (const float*)d_in[6];
  const float* w_proj1 = (const float*)d_in[7];
  const float* w_proj2 = (const float*)d_in[8];
  const float* ln_a = (const float*)d_in[9];
  const float* ln_b = (const float*)d_in[10];
  float* out = (float*)d_out;

  char* ws = (char*)d_ws;
  size_t off = 0;
  auto alloc = [&](size_t bytes) { char* p = ws + off; off += (bytes + 255) & ~(size_t)255; return p; };
  u16* X    = (u16*)alloc((size_t)TT * DMODEL * 2);    // live until proj (residual)
  u16* Qg   = (u16*)alloc((size_t)H * TT * 128 * 2);   // dead after attn -> Zb aliases
  u16* Kg   = (u16*)alloc((size_t)H * TT * 128 * 2);
  u16* Vtg  = (u16*)alloc((size_t)H * TT * 128 * 2);
  u16* W1t  = (u16*)alloc((size_t)1536 * 768 * 2);
  u16* W2t  = (u16*)alloc((size_t)1536 * 256 * 2);
  u16* Wpt  = (u16*)alloc((size_t)1024 * 512 * 2);
  u16* O1g  = (u16*)alloc((size_t)TT * 512 * 2);
  u16* O2g  = (u16*)alloc((size_t)TT * 512 * 2);
  u16* Zb   = Qg;  // exact alias of Qg (dead after attn)

  prep_kernel<<<16384, 256, 0, stream>>>(inp, X, w_qs1, w_ks1, w_vs1, w_qs2, w_ks2, w_vs2,
                                         w_proj1, w_proj2, W1t, W2t, Wpt);

  dim3 gq(64, 12);
  gemm_qkv<<<gq, 256, 0, stream>>>(X, W1t, W2t, Qg, Kg, Vtg);

  attn_kernel<<<512, 256, 81920, stream>>>(Qg, Kg, Vtg, O1g, O2g);

  dim3 gp(64, 8);
  gemm_proj<<<gp, 256, 0, stream>>>(O1g, O2g, Wpt, X, Zb);

  ln_kernel<<<TT, 256, 0, stream>>>(Zb, ln_a, ln_b, out);
}

// Round 13
// 124.725 us; speedup vs baseline: 1.1210x; 1.1210x over previous
//
#include <hip/hip_runtime.h>
#include <stdint.h>

#define H 8
#define DMODEL 1024
#define DCON 768
#define DPOS 256
#define TT 8192

typedef unsigned short u16;
typedef __attribute__((ext_vector_type(8))) short bf16x8;
typedef __attribute__((ext_vector_type(4))) short bf16x4;
typedef __attribute__((ext_vector_type(4))) float f32x4;

typedef __attribute__((address_space(1))) const void as1_void;
typedef __attribute__((address_space(3))) void as3_void;

__device__ __forceinline__ void async_copy16(const void* g, void* l) {
  __builtin_amdgcn_global_load_lds((as1_void*)g, (as3_void*)l, 16, 0, 0);
}

__device__ __forceinline__ short f2bf(float x) {
  unsigned u = __builtin_bit_cast(unsigned, x);
  u = (u + 0x7fffu + ((u >> 16) & 1u)) >> 16;
  return (short)u;
}

__device__ __forceinline__ short f2bf_trunc(float x) {
  return (short)(__builtin_bit_cast(unsigned, x) >> 16);
}

__device__ __forceinline__ float bf2f(u16 v) {
  return __builtin_bit_cast(float, (unsigned)v << 16);
}

// ---------------- fused prep kernel (one dispatch) ----------------
__global__ __launch_bounds__(256) void prep_kernel(
    const float* __restrict__ inp, u16* __restrict__ X,
    const float* __restrict__ wq1, const float* __restrict__ wk1, const float* __restrict__ wv1,
    const float* __restrict__ wq2, const float* __restrict__ wk2, const float* __restrict__ wv2,
    const float* __restrict__ wp1, const float* __restrict__ wp2,
    u16* __restrict__ W1t, u16* __restrict__ W2t, u16* __restrict__ Wpt) {
  const int bid = blockIdx.x, tid = threadIdx.x;
  if (bid < 8192) {
    size_t i = (size_t)bid * 256 + tid;
    const float4 v = *(const float4*)(inp + i * 4);
    bf16x4 o;
    o[0] = f2bf(v.x); o[1] = f2bf(v.y); o[2] = f2bf(v.z); o[3] = f2bf(v.w);
    *(bf16x4*)(X + i * 4) = o;
  } else if (bid < 14336) {
    const int w2 = (bid >= 12800);
    const int K = w2 ? 256 : 768;
    const float* wq = w2 ? wq2 : wq1;
    const float* wk = w2 ? wk2 : wk1;
    const float* wv = w2 ? wv2 : wv1;
    u16* Wt = w2 ? W2t : W1t;
    int idx = (bid - (w2 ? 12800 : 8192)) * 256 + tid;
    int n = idx / K, r = idx % K;
    int h = n / 192, rem = n % 192, op = rem >> 6, d = rem & 63;
    const float* src = (op == 0) ? wq : (op == 1) ? wk : wv;
    Wt[idx] = (u16)f2bf(src[((size_t)h * K + r) * 64 + d]);
  } else {
    const int p2 = (bid >= 15872);
    const float* w = p2 ? wp2 : wp1;
    const int Ncols = p2 ? 256 : 768;
    u16* Wt = Wpt + (p2 ? 768 * 512 : 0);
    int idx = (bid - (p2 ? 15872 : 14336)) * 256 + tid;
    int c = idx >> 9, j = idx & 511;
    Wt[idx] = (u16)f2bf(w[(size_t)j * Ncols + c]);
  }
}

// ---------------- merged QKV GEMM ----------------
__global__ __launch_bounds__(256) void gemm_qkv(
    const u16* __restrict__ Xb, const u16* __restrict__ W1t, const u16* __restrict__ W2t,
    u16* __restrict__ q_out, u16* __restrict__ k_out, u16* __restrict__ v_out) {
  __shared__ char smem[65536];
  auto Asp = [&](int buf) -> char* { return smem + buf * 16384; };
  auto Bsp = [&](int buf) -> char* { return smem + 32768 + buf * 16384; };
  const int tid = threadIdx.x;
  const int lane = tid & 63, wid = tid >> 6;
  const int m0 = blockIdx.x * 128;
  const int ny = blockIdx.y;
  const u16* Bt;
  int K, aoff, doff, n0;
  if (ny < 12) { Bt = W1t; K = 768; aoff = 0;   doff = 0;  n0 = ny * 128; }
  else         { Bt = W2t; K = 256; aoff = 768; doff = 64; n0 = (ny - 12) * 128; }
  const int KT = K >> 6;

  const int lr = lane >> 3, lcb = (lane & 7) << 4;

  auto stage = [&](int kt, int buf) {
#pragma unroll
    for (int s = 0; s < 4; ++s) {
      int r = wid * 32 + s * 8 + lr;
      int cb = lcb ^ ((r & 7) << 4);
      const char* g = (const char*)(Xb + (size_t)(m0 + r) * DMODEL + aoff + kt * 64) + cb;
      async_copy16(g, Asp(buf) + (wid * 32 + s * 8) * 128);
    }
#pragma unroll
    for (int s = 0; s < 4; ++s) {
      int r = wid * 32 + s * 8 + lr;
      int cb = lcb ^ ((r & 7) << 4);
      const char* g = (const char*)(Bt + (size_t)(n0 + r) * K + kt * 64) + cb;
      async_copy16(g, Bsp(buf) + (wid * 32 + s * 8) * 128);
    }
  };

  f32x4 acc[4][4];
  const f32x4 fz = {0.f, 0.f, 0.f, 0.f};
#pragma unroll
  for (int i = 0; i < 4; ++i)
#pragma unroll
    for (int j = 0; j < 4; ++j) acc[i][j] = fz;

  const int mwq = (wid >> 1) * 64, nwq = (wid & 1) * 64;
  const int ml = lane & 15, kg = (lane >> 4) << 4;

  auto compute = [&](int buf) {
#pragma unroll
    for (int ks = 0; ks < 2; ++ks) {
      bf16x8 af[4], bfr[4];
#pragma unroll
      for (int f = 0; f < 4; ++f) {
        int rowa = mwq + f * 16 + ml;
        af[f] = *(const bf16x8*)(Asp(buf) + rowa * 128 + ((ks * 64 + kg) ^ ((rowa & 7) << 4)));
        int rowb = nwq + f * 16 + ml;
        bfr[f] = *(const bf16x8*)(Bsp(buf) + rowb * 128 + ((ks * 64 + kg) ^ ((rowb & 7) << 4)));
      }
#pragma unroll
      for (int fm = 0; fm < 4; ++fm)
#pragma unroll
        for (int fn = 0; fn < 4; ++fn)
          acc[fm][fn] = __builtin_amdgcn_mfma_f32_16x16x32_bf16(af[fm], bfr[fn], acc[fm][fn], 0, 0, 0);
    }
  };

  stage(0, 0);
  __syncthreads();
  for (int kt = 0; kt < KT - 1; ++kt) {
    stage(kt + 1, (kt + 1) & 1);
    compute(kt & 1);
    __syncthreads();
  }
  compute((KT - 1) & 1);

#pragma unroll
  for (int fm = 0; fm < 4; ++fm) {
#pragma unroll
    for (int fn = 0; fn < 4; ++fn) {
      int nb = n0 + nwq + fn * 16;
      int h = nb / 192, rem = nb % 192, op = rem >> 6, db = rem & 63;
      int d = doff + db + ml;
      int t0 = m0 + mwq + fm * 16 + (lane >> 4) * 4;
      if (op == 2) {
        int b = t0 >> 10, l = t0 & 1023;
        bf16x4 o4;
#pragma unroll
        for (int r = 0; r < 4; ++r) o4[r] = f2bf(acc[fm][fn][r]);
        *(bf16x4*)(v_out + ((size_t)(h * 8 + b) * 128 + d) * 1024 + l) = o4;
      } else {
        u16* dst = (op == 0) ? q_out : k_out;
#pragma unroll
        for (int r = 0; r < 4; ++r)
          dst[((size_t)h * TT + t0 + r) * 128 + d] = (u16)f2bf(acc[fm][fn][r]);
      }
    }
  }
}

// ---------------- proj GEMM (bf16 Z epilogue) ----------------
__global__ __launch_bounds__(256) void gemm_proj(
    const u16* __restrict__ O1, const u16* __restrict__ O2, const u16* __restrict__ Wpt,
    const u16* __restrict__ Xb, u16* __restrict__ Zb) {
  __shared__ char smem[65536];
  auto Asp = [&](int buf) -> char* { return smem + buf * 16384; };
  auto Bsp = [&](int buf) -> char* { return smem + 32768 + buf * 16384; };
  const int tid = threadIdx.x;
  const int lane = tid & 63, wid = tid >> 6;
  const int m0 = blockIdx.x * 128, n0 = blockIdx.y * 128;
  const u16* A = (blockIdx.y < 6) ? O1 : O2;
  const int KT = 8;  // K = 512

  const int lr = lane >> 3, lcb = (lane & 7) << 4;

  auto stage = [&](int kt, int buf) {
#pragma unroll
    for (int s = 0; s < 4; ++s) {
      int r = wid * 32 + s * 8 + lr;
      int cb = lcb ^ ((r & 7) << 4);
      const char* g = (const char*)(A + (size_t)(m0 + r) * 512 + kt * 64) + cb;
      async_copy16(g, Asp(buf) + (wid * 32 + s * 8) * 128);
    }
#pragma unroll
    for (int s = 0; s < 4; ++s) {
      int r = wid * 32 + s * 8 + lr;
      int cb = lcb ^ ((r & 7) << 4);
      const char* g = (const char*)(Wpt + (size_t)(n0 + r) * 512 + kt * 64) + cb;
      async_copy16(g, Bsp(buf) + (wid * 32 + s * 8) * 128);
    }
  };

  f32x4 acc[4][4];
  const f32x4 fz = {0.f, 0.f, 0.f, 0.f};
#pragma unroll
  for (int i = 0; i < 4; ++i)
#pragma unroll
    for (int j = 0; j < 4; ++j) acc[i][j] = fz;

  const int mwq = (wid >> 1) * 64, nwq = (wid & 1) * 64;
  const int ml = lane & 15, kg = (lane >> 4) << 4;

  auto compute = [&](int buf) {
#pragma unroll
    for (int ks = 0; ks < 2; ++ks) {
      bf16x8 af[4], bfr[4];
#pragma unroll
      for (int f = 0; f < 4; ++f) {
        int rowa = mwq + f * 16 + ml;
        af[f] = *(const bf16x8*)(Asp(buf) + rowa * 128 + ((ks * 64 + kg) ^ ((rowa & 7) << 4)));
        int rowb = nwq + f * 16 + ml;
        bfr[f] = *(const bf16x8*)(Bsp(buf) + rowb * 128 + ((ks * 64 + kg) ^ ((rowb & 7) << 4)));
      }
#pragma unroll
      for (int fm = 0; fm < 4; ++fm)
#pragma unroll
        for (int fn = 0; fn < 4; ++fn)
          acc[fm][fn] = __builtin_amdgcn_mfma_f32_16x16x32_bf16(af[fm], bfr[fn], acc[fm][fn], 0, 0, 0);
    }
  };

  stage(0, 0);
  __syncthreads();
  for (int kt = 0; kt < KT - 1; ++kt) {
    stage(kt + 1, (kt + 1) & 1);
    compute(kt & 1);
    __syncthreads();
  }
  compute((KT - 1) & 1);

#pragma unroll
  for (int fm = 0; fm < 4; ++fm)
#pragma unroll
    for (int fn = 0; fn < 4; ++fn) {
      int col = n0 + nwq + fn * 16 + ml;
#pragma unroll
      for (int r = 0; r < 4; ++r) {
        int t = m0 + mwq + fm * 16 + (lane >> 4) * 4 + r;
        float zv = acc[fm][fn][r] + bf2f(Xb[(size_t)t * DMODEL + col]);
        Zb[(size_t)t * DMODEL + col] = (u16)f2bf(zv);
      }
    }
}

// ---------------- flash attention: 4 fat waves x 32 q-rows (frozen champion) ----------------
// grid 512 = qt(8) x hb(64); bid%8 == hb%8 (XCD-pinned K/V). 256 threads.
// LDS-staged K/V (double-buffered, counted-vmcnt 2-deep pipeline). Each kf/vf
// LDS read feeds both q-subtiles' MFMAs. Row-sum l via ones-vector MFMA.
__global__ __launch_bounds__(256, 2) void attn_kernel(
    const u16* __restrict__ Qg, const u16* __restrict__ Kg, const u16* __restrict__ Vtg,
    u16* __restrict__ O1g, u16* __restrict__ O2g) {
  extern __shared__ char smem[];
  const int tid = threadIdx.x, lane = tid & 63, wid = tid >> 6;
  const int bid = blockIdx.x;
  const int qt = bid >> 6, hb = bid & 63, h = hb >> 3, b = hb & 7;
  const int ml = lane & 15, kgrp = lane >> 4, kg = kgrp << 4;

  const size_t qkbase = ((size_t)h * TT + b * 1024) * 128;
  const char* Kbyte = (const char*)(Kg + qkbase);
  const char* Vbyte = (const char*)(Vtg + (size_t)hb * 128 * 1024);

  bf16x8 qf[2][4];
#pragma unroll
  for (int qs = 0; qs < 2; ++qs) {
    const char* qp = (const char*)(Qg + qkbase + (size_t)(qt * 128 + wid * 32 + qs * 16 + ml) * 128);
#pragma unroll
    for (int kk = 0; kk < 4; ++kk) qf[qs][kk] = *(const bf16x8*)(qp + kk * 64 + kg);
  }

  auto stage = [&](int kv0, int buf) {
#pragma unroll
    for (int s = 0; s < 4; ++s) {
      int c = wid * 256 + s * 64 + lane;
      int row = c >> 4, i16 = (c & 15) << 4;
      const char* g = Kbyte + (size_t)(kv0 + row) * 256 + (i16 ^ ((row & 7) << 4));
      async_copy16(g, smem + buf * 16384 + c * 16);
    }
#pragma unroll
    for (int s = 0; s < 4; ++s) {
      int c = wid * 256 + s * 64 + lane;
      int row = c >> 3, i16 = (c & 7) << 4;
      const char* g = Vbyte + (size_t)row * 2048 + kv0 * 2 + (i16 ^ ((row & 7) << 4));
      async_copy16(g, smem + 32768 + buf * 16384 + c * 16);
    }
  };

  f32x4 oacc[2][8];
  f32x4 lacc[2];
  const f32x4 fz = {0.f, 0.f, 0.f, 0.f};
#pragma unroll
  for (int qs = 0; qs < 2; ++qs) {
    lacc[qs] = fz;
#pragma unroll
    for (int i = 0; i < 8; ++i) oacc[qs][i] = fz;
  }
  const float C2 = 0.045084219952754514f;  // log2(e)/32
  bf16x8 ones;
#pragma unroll
  for (int j = 0; j < 8; ++j) ones[j] = (short)0x3F80;  // bf16 1.0

  char* Pw = smem + 65536 + wid * 4096;

  asm volatile("s_waitcnt vmcnt(0)" ::: "memory");
  stage(0, 0);
  stage(64, 1);

  for (int it = 0; it < 16; ++it) {
    const int cur = it & 1;
    if (it < 15) asm volatile("s_waitcnt vmcnt(8)" ::: "memory");
    else         asm volatile("s_waitcnt vmcnt(0)" ::: "memory");
    __builtin_amdgcn_sched_barrier(0);
    __builtin_amdgcn_s_barrier();
    __builtin_amdgcn_sched_barrier(0);

    f32x4 s4[2][4];
#pragma unroll
    for (int qs = 0; qs < 2; ++qs)
#pragma unroll
      for (int i = 0; i < 4; ++i) s4[qs][i] = fz;
    __builtin_amdgcn_s_setprio(1);
#pragma unroll
    for (int kk = 0; kk < 4; ++kk) {
#pragma unroll
      for (int rt = 0; rt < 4; ++rt) {
        int row = rt * 16 + ml;
        bf16x8 kf = *(const bf16x8*)(smem + cur * 16384 + row * 256 + ((kk * 64 + kg) ^ ((row & 7) << 4)));
        s4[0][rt] = __builtin_amdgcn_mfma_f32_16x16x32_bf16(kf, qf[0][kk], s4[0][rt], 0, 0, 0);
        s4[1][rt] = __builtin_amdgcn_mfma_f32_16x16x32_bf16(kf, qf[1][kk], s4[1][rt], 0, 0, 0);
      }
    }
    __builtin_amdgcn_s_setprio(0);

#pragma unroll
    for (int qs = 0; qs < 2; ++qs) {
#pragma unroll
      for (int rt = 0; rt < 4; ++rt) {
        bf16x4 pv;
#pragma unroll
        for (int r = 0; r < 4; ++r) pv[r] = f2bf_trunc(exp2f(s4[qs][rt][r] * C2));
        int cb = (rt * 32 + (kgrp << 3)) ^ ((ml & 7) << 4);
        *(bf16x4*)(Pw + qs * 2048 + ml * 128 + cb) = pv;
      }
    }

    bf16x8 pa[2][2];
#pragma unroll
    for (int qs = 0; qs < 2; ++qs)
#pragma unroll
      for (int ks = 0; ks < 2; ++ks)
        pa[qs][ks] = *(const bf16x8*)(Pw + qs * 2048 + ml * 128 + ((ks * 64 + kg) ^ ((ml & 7) << 4)));

    __builtin_amdgcn_s_setprio(1);
    lacc[0] = __builtin_amdgcn_mfma_f32_16x16x32_bf16(pa[0][0], ones, lacc[0], 0, 0, 0);
    lacc[0] = __builtin_amdgcn_mfma_f32_16x16x32_bf16(pa[0][1], ones, lacc[0], 0, 0, 0);
    lacc[1] = __builtin_amdgcn_mfma_f32_16x16x32_bf16(pa[1][0], ones, lacc[1], 0, 0, 0);
    lacc[1] = __builtin_amdgcn_mfma_f32_16x16x32_bf16(pa[1][1], ones, lacc[1], 0, 0, 0);
#pragma unroll
    for (int vt = 0; vt < 8; ++vt) {
#pragma unroll
      for (int ks = 0; ks < 2; ++ks) {
        int row = vt * 16 + ml;
        bf16x8 vf = *(const bf16x8*)(smem + 32768 + cur * 16384 + row * 128 + ((ks * 64 + kg) ^ ((row & 7) << 4)));
        oacc[0][vt] = __builtin_amdgcn_mfma_f32_16x16x32_bf16(pa[0][ks], vf, oacc[0][vt], 0, 0, 0);
        oacc[1][vt] = __builtin_amdgcn_mfma_f32_16x16x32_bf16(pa[1][ks], vf, oacc[1][vt], 0, 0, 0);
      }
    }
    __builtin_amdgcn_s_setprio(0);

    __builtin_amdgcn_sched_barrier(0);
    __builtin_amdgcn_s_barrier();
    __builtin_amdgcn_sched_barrier(0);
    if (it < 14) stage((it + 2) * 64, cur);
  }

#pragma unroll
  for (int qs = 0; qs < 2; ++qs) {
    float rl[4];
#pragma unroll
    for (int r = 0; r < 4; ++r) rl[r] = 1.f / lacc[qs][r];
#pragma unroll
    for (int vt = 0; vt < 8; ++vt) {
#pragma unroll
      for (int r = 0; r < 4; ++r) {
        int trow = b * 1024 + qt * 128 + wid * 32 + qs * 16 + kgrp * 4 + r;
        float ov = oacc[qs][vt][r] * rl[r];
        if (vt < 4)
          O1g[(size_t)trow * 512 + h * 64 + vt * 16 + ml] = (u16)f2bf(ov);
        else
          O2g[(size_t)trow * 512 + h * 64 + (vt - 4) * 16 + ml] = (u16)f2bf(ov);
      }
    }
  }
}

// ---------------- layernorm (bf16 Z input) ----------------
__global__ __launch_bounds__(256) void ln_kernel(const u16* __restrict__ Zb, const float* __restrict__ ga,
                                                 const float* __restrict__ gb, float* __restrict__ out) {
  int row = blockIdx.x, tid = threadIdx.x;
  bf16x4 zv = *(const bf16x4*)(Zb + (size_t)row * 1024 + tid * 4);
  float v0 = bf2f((u16)zv[0]), v1 = bf2f((u16)zv[1]), v2 = bf2f((u16)zv[2]), v3 = bf2f((u16)zv[3]);
  float s = v0 + v1 + v2 + v3;
  float s2 = v0 * v0 + v1 * v1 + v2 * v2 + v3 * v3;
#pragma unroll
  for (int d = 1; d < 64; d <<= 1) {
    s += __shfl_xor(s, d);
    s2 += __shfl_xor(s2, d);
  }
  __shared__ float red[8];
  int wid = tid >> 6, lane = tid & 63;
  if (lane == 0) { red[wid] = s; red[4 + wid] = s2; }
  __syncthreads();
  float ts = red[0] + red[1] + red[2] + red[3];
  float ts2 = red[4] + red[5] + red[6] + red[7];
  float mu = ts * (1.f / 1024.f);
  float var = (ts2 - ts * mu) * (1.f / 1023.f);
  float inv = 1.f / (sqrtf(var) + 0.001f);
  const float4 a = *(const float4*)(ga + tid * 4);
  const float4 bb = *(const float4*)(gb + tid * 4);
  float4 o;
  o.x = (v0 - mu) * inv * a.x + bb.x;
  o.y = (v1 - mu) * inv * a.y + bb.y;
  o.z = (v2 - mu) * inv * a.z + bb.z;
  o.w = (v3 - mu) * inv * a.w + bb.w;
  *(float4*)(out + (size_t)row * 1024 + tid * 4) = o;
}

// ---------------- launch ----------------
extern "C" void kernel_launch(void* const* d_in, const int* in_sizes, int n_in,
                              void* d_out, int out_size, void* d_ws, size_t ws_size,
                              hipStream_t stream) {
  (void)in_sizes; (void)n_in; (void)out_size; (void)ws_size;
  const float* inp = (const float*)d_in[0];
  const float* w_qs1 = (const float*)d_in[1];
  const float* w_ks1 = (const float*)d_in[2];
  const float* w_vs1 = (const float*)d_in[3];
  const float* w_qs2 = (const float*)d_in[4];
  const float* w_ks2 = (const float*)d_in[5];
  const float* w_vs2 = (const float*)d_in[6];
  const float* w_proj1 = (const float*)d_in[7];
  const float* w_proj2 = (const float*)d_in[8];
  const float* ln_a = (const float*)d_in[9];
  const float* ln_b = (const float*)d_in[10];
  float* out = (float*)d_out;

  char* ws = (char*)d_ws;
  size_t off = 0;
  auto alloc = [&](size_t bytes) { char* p = ws + off; off += (bytes + 255) & ~(size_t)255; return p; };
  u16* X    = (u16*)alloc((size_t)TT * DMODEL * 2);    // live until proj (residual)
  u16* Qg   = (u16*)alloc((size_t)H * TT * 128 * 2);   // dead after attn -> Zb aliases
  u16* Kg   = (u16*)alloc((size_t)H * TT * 128 * 2);
  u16* Vtg  = (u16*)alloc((size_t)H * TT * 128 * 2);
  u16* W1t  = (u16*)alloc((size_t)1536 * 768 * 2);
  u16* W2t  = (u16*)alloc((size_t)1536 * 256 * 2);
  u16* Wpt  = (u16*)alloc((size_t)1024 * 512 * 2);
  u16* O1g  = (u16*)alloc((size_t)TT * 512 * 2);
  u16* O2g  = (u16*)alloc((size_t)TT * 512 * 2);
  u16* Zb   = Qg;  // exact alias of Qg (dead after attn)

  prep_kernel<<<16384, 256, 0, stream>>>(inp, X, w_qs1, w_ks1, w_vs1, w_qs2, w_ks2, w_vs2,
                                         w_proj1, w_proj2, W1t, W2t, Wpt);

  dim3 gq(64, 24);
  gemm_qkv<<<gq, 256, 0, stream>>>(X, W1t, W2t, Qg, Kg, Vtg);

  attn_kernel<<<512, 256, 81920, stream>>>(Qg, Kg, Vtg, O1g, O2g);

  dim3 gp(64, 8);
  gemm_proj<<<gp, 256, 0, stream>>>(O1g, O2g, Wpt, X, Zb);

  ln_kernel<<<TT, 256, 0, stream>>>(Zb, ln_a, ln_b, out);
}